// Round 6
// baseline (272.235 us; speedup 1.0000x reference)
//
#include <hip/hip_runtime.h>

#define N_NODES 100000
#define N_EDGES 1600000
#define IN_DIM 32
#define HID_DIM 64
#define OUT_DIM 8
#define BK 128                        // dst nodes per bucket
#define NBKT ((N_NODES + BK - 1) / BK)    // 782
#define QC 2560                       // per-bucket queue cap (mean 2048, ~11 sigma)
#define CHUNK 4096                    // edges per k_part2 block
#define NCHUNK ((N_EDGES + CHUNK - 1) / CHUNK)   // 391

typedef unsigned short u16;
typedef unsigned int u32;
typedef unsigned long long ull;

__device__ __forceinline__ float bf2f(u16 v) {
    return __uint_as_float(((u32)v) << 16);
}

__device__ __forceinline__ u16 f2bf(float f) {
    u32 u = __float_as_uint(f);
    u32 lsb = (u >> 16) & 1u;
    u += 0x7fffu + lsb;
    return (u16)(u >> 16);
}

__device__ __forceinline__ float ldf(const void* p, size_t i, int bf) {
    return bf ? bf2f(((const u16*)p)[i]) : ((const float*)p)[i];
}

// ---- Phase A (R3/R5-proven): dtype probe + weight transpose + single-pass
//      partition of edges into 782 dst-buckets of 128 nodes ((src<<7)|d7). ----
__global__ __launch_bounds__(256) void k_part2(
    const int* __restrict__ ei, const u32* __restrict__ xw,
    const void* __restrict__ W1l, const void* __restrict__ b1,
    const void* __restrict__ W1r,
    const void* __restrict__ W2l, const void* __restrict__ b2,
    const void* __restrict__ W2r,
    int* __restrict__ qcnt, u32* __restrict__ qbuf,
    float* __restrict__ tW1l, float* __restrict__ tW1r,
    float* __restrict__ tW2l, float* __restrict__ tW2r,
    float* __restrict__ tb1, float* __restrict__ tb2)
{
    __shared__ int shv, bfv;
    __shared__ int hist[NBKT], gbase[NBKT], lcur[NBKT];
    int t = threadIdx.x;
    if (t < 64) {   // proven dtype probe, executed per block (same data)
        int v = ei[2 * t + 1];
        ull m1 = __ballot(v == 0);
        u32 wd = xw[t];
        u32 b = (wd >> 8) & 0x7fu;
        ull m2 = __ballot(b >= 0x38u && b <= 0x41u);
        if (t == 0) {
            shv = (m1 == ~0ULL) ? 1 : 0;
            bfv = (__popcll(m2) >= 56) ? 1 : 0;
        }
    }
    for (int i = t; i < NBKT; i += 256) { hist[i] = 0; lcur[i] = 0; }
    __syncthreads();
    int sh = shv, bf = bfv;

    if (blockIdx.x < 16) {        // weight transpose duty (R11-proven indexing)
        for (int i = blockIdx.x * 256 + t; i < HID_DIM * IN_DIM; i += 16 * 256) {
            int o = i / IN_DIM, k = i % IN_DIM;
            tW1l[k * HID_DIM + o] = ldf(W1l, i, bf);
            tW1r[k * HID_DIM + o] = ldf(W1r, i, bf);
        }
        for (int i = blockIdx.x * 256 + t; i < OUT_DIM * HID_DIM; i += 16 * 256) {
            int o = i / HID_DIM, k = i % HID_DIM;
            tW2l[k * OUT_DIM + o] = ldf(W2l, i, bf);
            tW2r[k * OUT_DIM + o] = ldf(W2r, i, bf);
        }
        if (blockIdx.x == 0) {
            if (t < HID_DIM) tb1[t] = ldf(b1, t, bf);
            if (t < OUT_DIM) tb2[t] = ldf(b2, t, bf);
        }
    }

    // edge partition (register-staged, R10-proven shape)
    int e0 = blockIdx.x * CHUNK;
    int myd[16], mys[16];
    #pragma unroll
    for (int i = 0; i < 16; i++) {
        int e = e0 + i * 256 + t;
        if (e < N_EDGES) {
            size_t off = (size_t)e << sh;
            mys[i] = ei[off];
            int d = ei[((size_t)N_EDGES << sh) + off];
            myd[i] = d;
            atomicAdd(&hist[d >> 7], 1);
        } else myd[i] = -1;
    }
    __syncthreads();
    for (int i = t; i < NBKT; i += 256) {
        int h = hist[i];
        gbase[i] = h ? atomicAdd(&qcnt[i], h) : 0;
    }
    __syncthreads();
    #pragma unroll
    for (int i = 0; i < 16; i++) {
        int d = myd[i];
        if (d >= 0) {
            int bk = d >> 7;
            int p = gbase[bk] + atomicAdd(&lcur[bk], 1);
            if (p < QC)
                qbuf[(size_t)bk * QC + p] = ((u32)mys[i] << 7) | (u32)(d & 127);
        }
    }
}

// ---- Layer 1: one bucket (128 dst nodes) per block, now 512 threads
//      (8 waves) to double outstanding loads: R5 measured k_l1 latency-
//      bound (Occ 28.7%, HBM 10%, VALU 35% — 782 blocks = 3/CU was the cap).
//      (1) LDS counting sort of the bucket's edges by dst.
//      (2) R0-proven register-accumulate gather (4-way ILP) from sorted LDS.
//      (3) R3-proven dense1+relu+proj2 per node pair, wave-private bufs. ----
__global__ __launch_bounds__(512, 8) void k_l1(
    const void* __restrict__ x,
    const int* __restrict__ qcnt, const u32* __restrict__ qbuf,
    const float* __restrict__ tW1l, const float* __restrict__ tW1r,
    const float* __restrict__ tW2l, const float* __restrict__ tW2r,
    const float* __restrict__ tb1, const float* __restrict__ tb2,
    u16* __restrict__ gbuf, float* __restrict__ rbuf,
    const u32* __restrict__ xw)
{
    __shared__ int hist[BK], pos[BK], pcur[BK];
    __shared__ u32 srt[QC];                 // 10.2 KB sorted src lists
    __shared__ float xs[BK][IN_DIM];        // 16 KB self rows (f32)
    __shared__ float aggw[8][2][IN_DIM];    // 2 KB wave-private agg pair
    __shared__ float hb[16][HID_DIM + 1];   // 4.2 KB wave-private h rows
    __shared__ int wtot, bfv;

    int t = threadIdx.x;
    if (t < 64) {   // dtype probe (proven)
        u32 wd = xw[t];
        u32 b = (wd >> 8) & 0x7fu;
        ull m2 = __ballot(b >= 0x38u && b <= 0x41u);
        if (t == 0) bfv = (__popcll(m2) >= 56) ? 1 : 0;
    }
    if (t < BK) hist[t] = 0;
    __syncthreads();
    int bf = bfv;
    int b = blockIdx.x, nb = b * BK;
    int m = qcnt[b]; if (m > QC) m = QC; if (m < 0) m = 0;
    const u32* q = qbuf + (size_t)b * QC;

    // stage self rows -> xs (f32), guarded for the partial last bucket
    if (bf) {
        const u32* xr = (const u32*)x + (size_t)nb * (IN_DIM / 2);
        int lim = ((N_NODES - nb < BK) ? (N_NODES - nb) : BK) * (IN_DIM / 2);
        for (int i = t; i < BK * (IN_DIM / 2); i += 512) {
            u32 w = (i < lim) ? xr[i] : 0u;
            int r = i >> 4, c = i & 15;
            xs[r][2 * c]     = bf2f((u16)w);
            xs[r][2 * c + 1] = bf2f((u16)(w >> 16));
        }
    } else {
        const float* xr = (const float*)x + (size_t)nb * IN_DIM;
        int lim = ((N_NODES - nb < BK) ? (N_NODES - nb) : BK) * IN_DIM;
        for (int i = t; i < BK * IN_DIM; i += 512)
            xs[i >> 5][i & 31] = (i < lim) ? xr[i] : 0.0f;
    }

    // ---- counting sort: histogram -> scan -> scatter ----
    for (int i = t; i < m; i += 512)
        atomicAdd(&hist[q[i] & 127], 1);          // ~2K atomics total, cheap
    __syncthreads();
    int inc = 0, v = 0;
    if (t < 128) {                                 // 2-wave scan of 128 bins
        v = hist[t]; inc = v;
        #pragma unroll
        for (int o = 1; o < 64; o <<= 1) {
            int y = __shfl_up(inc, o, 64);
            if ((t & 63) >= o) inc += y;
        }
        if (t == 63) wtot = inc;
    }
    __syncthreads();
    if (t < 128) {
        int ex = ((t >= 64) ? wtot : 0) + inc - v;
        pos[t] = ex; pcur[t] = ex;
    }
    __syncthreads();
    for (int i = t; i < m; i += 512) {            // scatter src into sorted lists
        u32 u = q[i];                             // L2-hot second pass
        int p = atomicAdd(&pcur[u & 127], 1);
        srt[p] = u >> 7;
    }
    __syncthreads();

    // ---- per-pair gather (R0-proven loop, LDS slot lists) + dense + proj ----
    int wid = t >> 6, lane = t & 63;               // wid 0..7
    int half = lane >> 5, g2 = (lane >> 3) & 3, l = lane & 7;
    int o = lane;
    float bb = tb1[o];
    for (int pr = 0; pr < 8; pr++) {
        int s0 = pr * 16 + wid * 2;
        int ns = s0 + half;
        int st = pos[ns], deg = hist[ns];
        float a0 = 0, a1 = 0, a2 = 0, a3 = 0;
        float c0 = 0, c1 = 0, c2 = 0, c3 = 0;
        float d0 = 0, d1 = 0, d2 = 0, d3 = 0;
        float e0 = 0, e1 = 0, e2 = 0, e3 = 0;
        int j = g2;
        for (; j + 12 < deg; j += 16) {   // 4 independent neighbor loads in flight
            int sA = (int)srt[st + j];
            int sB = (int)srt[st + j + 4];
            int sC = (int)srt[st + j + 8];
            int sD = (int)srt[st + j + 12];
            if (bf) {
                ushort4 vA = reinterpret_cast<const ushort4*>((const u16*)x + (size_t)sA * IN_DIM)[l];
                ushort4 vB = reinterpret_cast<const ushort4*>((const u16*)x + (size_t)sB * IN_DIM)[l];
                ushort4 vC = reinterpret_cast<const ushort4*>((const u16*)x + (size_t)sC * IN_DIM)[l];
                ushort4 vD = reinterpret_cast<const ushort4*>((const u16*)x + (size_t)sD * IN_DIM)[l];
                a0 += bf2f(vA.x); a1 += bf2f(vA.y); a2 += bf2f(vA.z); a3 += bf2f(vA.w);
                c0 += bf2f(vB.x); c1 += bf2f(vB.y); c2 += bf2f(vB.z); c3 += bf2f(vB.w);
                d0 += bf2f(vC.x); d1 += bf2f(vC.y); d2 += bf2f(vC.z); d3 += bf2f(vC.w);
                e0 += bf2f(vD.x); e1 += bf2f(vD.y); e2 += bf2f(vD.z); e3 += bf2f(vD.w);
            } else {
                float4 vA = reinterpret_cast<const float4*>((const float*)x + (size_t)sA * IN_DIM)[l];
                float4 vB = reinterpret_cast<const float4*>((const float*)x + (size_t)sB * IN_DIM)[l];
                float4 vC = reinterpret_cast<const float4*>((const float*)x + (size_t)sC * IN_DIM)[l];
                float4 vD = reinterpret_cast<const float4*>((const float*)x + (size_t)sD * IN_DIM)[l];
                a0 += vA.x; a1 += vA.y; a2 += vA.z; a3 += vA.w;
                c0 += vB.x; c1 += vB.y; c2 += vB.z; c3 += vB.w;
                d0 += vC.x; d1 += vC.y; d2 += vC.z; d3 += vC.w;
                e0 += vD.x; e1 += vD.y; e2 += vD.z; e3 += vD.w;
            }
        }
        for (; j + 4 < deg; j += 8) {     // 2-way remainder
            int sA = (int)srt[st + j];
            int sB = (int)srt[st + j + 4];
            if (bf) {
                ushort4 vA = reinterpret_cast<const ushort4*>((const u16*)x + (size_t)sA * IN_DIM)[l];
                ushort4 vB = reinterpret_cast<const ushort4*>((const u16*)x + (size_t)sB * IN_DIM)[l];
                a0 += bf2f(vA.x); a1 += bf2f(vA.y); a2 += bf2f(vA.z); a3 += bf2f(vA.w);
                c0 += bf2f(vB.x); c1 += bf2f(vB.y); c2 += bf2f(vB.z); c3 += bf2f(vB.w);
            } else {
                float4 vA = reinterpret_cast<const float4*>((const float*)x + (size_t)sA * IN_DIM)[l];
                float4 vB = reinterpret_cast<const float4*>((const float*)x + (size_t)sB * IN_DIM)[l];
                a0 += vA.x; a1 += vA.y; a2 += vA.z; a3 += vA.w;
                c0 += vB.x; c1 += vB.y; c2 += vB.z; c3 += vB.w;
            }
        }
        if (j < deg) {                    // tail (at most one per group)
            int s = (int)srt[st + j];
            if (bf) {
                ushort4 vv = reinterpret_cast<const ushort4*>((const u16*)x + (size_t)s * IN_DIM)[l];
                a0 += bf2f(vv.x); a1 += bf2f(vv.y); a2 += bf2f(vv.z); a3 += bf2f(vv.w);
            } else {
                float4 vv = reinterpret_cast<const float4*>((const float*)x + (size_t)s * IN_DIM)[l];
                a0 += vv.x; a1 += vv.y; a2 += vv.z; a3 += vv.w;
            }
        }
        a0 += c0 + d0 + e0;
        a1 += c1 + d1 + e1;
        a2 += c2 + d2 + e2;
        a3 += c3 + d3 + e3;
        a0 += __shfl_xor(a0, 8, 64);  a0 += __shfl_xor(a0, 16, 64);
        a1 += __shfl_xor(a1, 8, 64);  a1 += __shfl_xor(a1, 16, 64);
        a2 += __shfl_xor(a2, 8, 64);  a2 += __shfl_xor(a2, 16, 64);
        a3 += __shfl_xor(a3, 8, 64);  a3 += __shfl_xor(a3, 16, 64);
        if (g2 == 0) {                    // wave-private: no barrier needed
            aggw[wid][half][4 * l + 0] = a0; aggw[wid][half][4 * l + 1] = a1;
            aggw[wid][half][4 * l + 2] = a2; aggw[wid][half][4 * l + 3] = a3;
        }
        // dense layer 1 (each lane = output o, both nodes of the pair)
        float rd0 = 1.0f / fmaxf((float)hist[s0], 1.0f);
        float rd1 = 1.0f / fmaxf((float)hist[s0 + 1], 1.0f);
        float acc0 = bb, acc1 = bb;
        #pragma unroll 8
        for (int k = 0; k < IN_DIM; k++) {
            float wl = tW1l[k * HID_DIM + o];
            float wr = tW1r[k * HID_DIM + o];
            acc0 += (aggw[wid][0][k] * rd0) * wl + xs[s0][k] * wr;
            acc1 += (aggw[wid][1][k] * rd1) * wl + xs[s0 + 1][k] * wr;
        }
        hb[wid * 2][o]     = fmaxf(acc0, 0.0f);   // wave-private rows
        hb[wid * 2 + 1][o] = fmaxf(acc1, 0.0f);
        // layer-2 projections: g = h@W2l^T (bf16-packed), r = h@W2r^T + b2
        int hs = wid * 2 + half;
        float ga = 0.0f, ra = 0.0f;
        #pragma unroll 4
        for (int mm = 0; mm < 16; mm++) {
            int k = g2 * 16 + mm;
            float hv = hb[hs][k];
            ga += hv * tW2l[k * OUT_DIM + l];
            ra += hv * tW2r[k * OUT_DIM + l];
        }
        ga += __shfl_xor(ga, 8, 64);  ga += __shfl_xor(ga, 16, 64);
        ra += __shfl_xor(ra, 8, 64);  ra += __shfl_xor(ra, 16, 64);
        int n = nb + ns;
        if (g2 == 0 && n < N_NODES) {
            __builtin_nontemporal_store(f2bf(ga), &gbuf[(size_t)n * OUT_DIM + l]);
            __builtin_nontemporal_store(ra + tb2[l], &rbuf[(size_t)n * OUT_DIM + l]);
        }
    }
}

// ---- Layer 2 (R5-proven): one bucket per block. Counting sort, then gather
//      g[src] rows (L2-resident 1.6MB) with the 8-lane/node 4-way-ILP loop. ----
__global__ __launch_bounds__(256) void k_l2(
    const u16* __restrict__ gbuf, const float* __restrict__ rbuf,
    const int* __restrict__ qcnt, const u32* __restrict__ qbuf,
    const u32* __restrict__ xw, void* __restrict__ out)
{
    __shared__ int hist[BK], pos[BK], pcur[BK];
    __shared__ u32 srt[QC];
    __shared__ int wtot, bfv;
    int t = threadIdx.x;
    if (t < 64) {   // output-dtype probe (proven)
        u32 w = xw[t];
        u32 b = (w >> 8) & 0x7fu;
        ull m2 = __ballot(b >= 0x38u && b <= 0x41u);
        if (t == 0) bfv = (__popcll(m2) >= 56) ? 1 : 0;
    }
    if (t < BK) hist[t] = 0;
    __syncthreads();
    int b = blockIdx.x, nb = b * BK;
    int m = qcnt[b]; if (m > QC) m = QC; if (m < 0) m = 0;
    const u32* q = qbuf + (size_t)b * QC;

    for (int i = t; i < m; i += 256)
        atomicAdd(&hist[q[i] & 127], 1);
    __syncthreads();
    int inc = 0, v = 0;
    if (t < 128) {
        v = hist[t]; inc = v;
        #pragma unroll
        for (int o = 1; o < 64; o <<= 1) {
            int y = __shfl_up(inc, o, 64);
            if ((t & 63) >= o) inc += y;
        }
        if (t == 63) wtot = inc;
    }
    __syncthreads();
    if (t < 128) {
        int ex = ((t >= 64) ? wtot : 0) + inc - v;
        pos[t] = ex; pcur[t] = ex;
    }
    __syncthreads();
    for (int i = t; i < m; i += 256) {
        u32 u = q[i];
        int p = atomicAdd(&pcur[u & 127], 1);
        srt[p] = u >> 7;
    }
    __syncthreads();

    int grp = t >> 3, l = t & 7;          // 32 groups x 8 lanes
    for (int r = 0; r < 4; r++) {
        int ns = grp * 4 + r;             // node slot 0..127
        int st = pos[ns], deg = hist[ns];
        float a0 = 0.0f, a1 = 0.0f, a2 = 0.0f, a3 = 0.0f;
        int j = 0;
        for (; j + 3 < deg; j += 4) {
            int v0 = (int)srt[st + j];
            int v1 = (int)srt[st + j + 1];
            int v2 = (int)srt[st + j + 2];
            int v3 = (int)srt[st + j + 3];
            a0 += bf2f(gbuf[(size_t)v0 * OUT_DIM + l]);
            a1 += bf2f(gbuf[(size_t)v1 * OUT_DIM + l]);
            a2 += bf2f(gbuf[(size_t)v2 * OUT_DIM + l]);
            a3 += bf2f(gbuf[(size_t)v3 * OUT_DIM + l]);
        }
        for (; j < deg; j++) a0 += bf2f(gbuf[(size_t)srt[st + j] * OUT_DIM + l]);
        int n = nb + ns;
        if (n < N_NODES) {
            float res = (a0 + a1 + a2 + a3) / fmaxf((float)deg, 1.0f)
                      + rbuf[(size_t)n * OUT_DIM + l];
            size_t oi = (size_t)n * OUT_DIM + l;
            if (bfv) ((u16*)out)[oi] = f2bf(res);
            else     ((float*)out)[oi] = res;
        }
    }
}

extern "C" void kernel_launch(void* const* d_in, const int* in_sizes, int n_in,
                              void* d_out, int out_size, void* d_ws, size_t ws_size,
                              hipStream_t stream) {
    const void* x   = d_in[0];
    const int*  ei  = (const int*)d_in[1];
    const void* W1l = d_in[2];
    const void* b1  = d_in[3];
    const void* W1r = d_in[4];
    const void* W2l = d_in[5];
    const void* b2  = d_in[6];
    const void* W2r = d_in[7];

    // ws layout (4B units); total ~13 MB (ws >= 64.4 MB proven earlier)
    int* qcnt    = (int*)d_ws;                       // 1024 (memset, 782 used)
    float* tW1l  = (float*)(qcnt + 1024);            // 2048
    float* tW1r  = tW1l + IN_DIM * HID_DIM;          // 2048
    float* tW2l  = tW1r + IN_DIM * HID_DIM;          // 512
    float* tW2r  = tW2l + HID_DIM * OUT_DIM;         // 512
    float* tb1   = tW2r + HID_DIM * OUT_DIM;         // 64
    float* tb2   = tb1 + HID_DIM;                    // 8
    u32* qbuf    = (u32*)(tb2 + OUT_DIM);            // NBKT*QC (8.0 MB, 16B-aligned)
    u16* gbuf    = (u16*)(qbuf + (size_t)NBKT * QC);           // N*8 u16 (1.6 MB)
    float* rbuf  = (float*)(gbuf + (size_t)N_NODES * OUT_DIM); // N*8 f32 (3.2 MB)

    // zero qcnt only (4 KB)
    hipMemsetAsync(d_ws, 0, 1024 * sizeof(int), stream);

    k_part2<<<NCHUNK, 256, 0, stream>>>(ei, (const u32*)x,
                                        W1l, b1, W1r, W2l, b2, W2r,
                                        qcnt, qbuf,
                                        tW1l, tW1r, tW2l, tW2r, tb1, tb2);
    k_l1<<<NBKT, 512, 0, stream>>>(x, qcnt, qbuf,
                                   tW1l, tW1r, tW2l, tW2r, tb1, tb2,
                                   gbuf, rbuf, (const u32*)x);
    k_l2<<<NBKT, 256, 0, stream>>>(gbuf, rbuf, qcnt, qbuf,
                                   (const u32*)x, d_out);
}

// Round 7
// 217.104 us; speedup vs baseline: 1.2539x; 1.2539x over previous
//
#include <hip/hip_runtime.h>

#define N_NODES 100000
#define N_EDGES 1600000
#define IN_DIM 32
#define HID_DIM 64
#define OUT_DIM 8
#define BK 128                        // dst nodes per bucket
#define NBKT ((N_NODES + BK - 1) / BK)    // 782
#define QC 2560                       // per-bucket queue cap (mean 2048, ~11 sigma)
#define CHUNK 4096                    // edges per k_part2 block
#define NCHUNK ((N_EDGES + CHUNK - 1) / CHUNK)   // 391

typedef unsigned short u16;
typedef unsigned int u32;
typedef unsigned long long ull;

__device__ __forceinline__ float bf2f(u16 v) {
    return __uint_as_float(((u32)v) << 16);
}

__device__ __forceinline__ u16 f2bf(float f) {
    u32 u = __float_as_uint(f);
    u32 lsb = (u >> 16) & 1u;
    u += 0x7fffu + lsb;
    return (u16)(u >> 16);
}

__device__ __forceinline__ float ldf(const void* p, size_t i, int bf) {
    return bf ? bf2f(((const u16*)p)[i]) : ((const float*)p)[i];
}

// ---- Phase A (R3/R5-proven): dtype probe + weight transpose + single-pass
//      partition of edges into 782 dst-buckets of 128 nodes ((src<<7)|d7). ----
__global__ __launch_bounds__(256) void k_part2(
    const int* __restrict__ ei, const u32* __restrict__ xw,
    const void* __restrict__ W1l, const void* __restrict__ b1,
    const void* __restrict__ W1r,
    const void* __restrict__ W2l, const void* __restrict__ b2,
    const void* __restrict__ W2r,
    int* __restrict__ qcnt, u32* __restrict__ qbuf,
    float* __restrict__ tW1l, float* __restrict__ tW1r,
    float* __restrict__ tW2l, float* __restrict__ tW2r,
    float* __restrict__ tb1, float* __restrict__ tb2)
{
    __shared__ int shv, bfv;
    __shared__ int hist[NBKT], gbase[NBKT], lcur[NBKT];
    int t = threadIdx.x;
    if (t < 64) {   // proven dtype probe, executed per block (same data)
        int v = ei[2 * t + 1];
        ull m1 = __ballot(v == 0);
        u32 wd = xw[t];
        u32 b = (wd >> 8) & 0x7fu;
        ull m2 = __ballot(b >= 0x38u && b <= 0x41u);
        if (t == 0) {
            shv = (m1 == ~0ULL) ? 1 : 0;
            bfv = (__popcll(m2) >= 56) ? 1 : 0;
        }
    }
    for (int i = t; i < NBKT; i += 256) { hist[i] = 0; lcur[i] = 0; }
    __syncthreads();
    int sh = shv, bf = bfv;

    if (blockIdx.x < 16) {        // weight transpose duty (R11-proven indexing)
        for (int i = blockIdx.x * 256 + t; i < HID_DIM * IN_DIM; i += 16 * 256) {
            int o = i / IN_DIM, k = i % IN_DIM;
            tW1l[k * HID_DIM + o] = ldf(W1l, i, bf);
            tW1r[k * HID_DIM + o] = ldf(W1r, i, bf);
        }
        for (int i = blockIdx.x * 256 + t; i < OUT_DIM * HID_DIM; i += 16 * 256) {
            int o = i / HID_DIM, k = i % HID_DIM;
            tW2l[k * OUT_DIM + o] = ldf(W2l, i, bf);
            tW2r[k * OUT_DIM + o] = ldf(W2r, i, bf);
        }
        if (blockIdx.x == 0) {
            if (t < HID_DIM) tb1[t] = ldf(b1, t, bf);
            if (t < OUT_DIM) tb2[t] = ldf(b2, t, bf);
        }
    }

    // edge partition (register-staged, R10-proven shape)
    int e0 = blockIdx.x * CHUNK;
    int myd[16], mys[16];
    #pragma unroll
    for (int i = 0; i < 16; i++) {
        int e = e0 + i * 256 + t;
        if (e < N_EDGES) {
            size_t off = (size_t)e << sh;
            mys[i] = ei[off];
            int d = ei[((size_t)N_EDGES << sh) + off];
            myd[i] = d;
            atomicAdd(&hist[d >> 7], 1);
        } else myd[i] = -1;
    }
    __syncthreads();
    for (int i = t; i < NBKT; i += 256) {
        int h = hist[i];
        gbase[i] = h ? atomicAdd(&qcnt[i], h) : 0;
    }
    __syncthreads();
    #pragma unroll
    for (int i = 0; i < 16; i++) {
        int d = myd[i];
        if (d >= 0) {
            int bk = d >> 7;
            int p = gbase[bk] + atomicAdd(&lcur[bk], 1);
            if (p < QC)
                qbuf[(size_t)bk * QC + p] = ((u32)mys[i] << 7) | (u32)(d & 127);
        }
    }
}

// ---- Layer 1: one bucket (128 dst nodes) per block, 512 threads (8 waves).
//      R6 lesson: __launch_bounds__(512,8) squeezed VGPR to 32 -> spills
//      (WRITE 7->89MB, FETCH 79->261MB). (512,4) keeps ~56 VGPR, no spill;
//      occupancy stays grid/LDS-limited at ~24 waves/CU (R6 measured 62%).
//      (1) LDS counting sort of the bucket's edges by dst.
//      (2) R0-proven register-accumulate gather (4-way ILP) from sorted LDS.
//      (3) R3-proven dense1+relu+proj2 per node pair, wave-private bufs. ----
__global__ __launch_bounds__(512, 4) void k_l1(
    const void* __restrict__ x,
    const int* __restrict__ qcnt, const u32* __restrict__ qbuf,
    const float* __restrict__ tW1l, const float* __restrict__ tW1r,
    const float* __restrict__ tW2l, const float* __restrict__ tW2r,
    const float* __restrict__ tb1, const float* __restrict__ tb2,
    u16* __restrict__ gbuf, float* __restrict__ rbuf,
    const u32* __restrict__ xw)
{
    __shared__ int hist[BK], pos[BK], pcur[BK];
    __shared__ u32 srt[QC];                 // 10.2 KB sorted src lists
    __shared__ float xs[BK][IN_DIM];        // 16 KB self rows (f32)
    __shared__ float aggw[8][2][IN_DIM];    // 2 KB wave-private agg pair
    __shared__ float hb[16][HID_DIM + 1];   // 4.2 KB wave-private h rows
    __shared__ int wtot, bfv;

    int t = threadIdx.x;
    if (t < 64) {   // dtype probe (proven)
        u32 wd = xw[t];
        u32 b = (wd >> 8) & 0x7fu;
        ull m2 = __ballot(b >= 0x38u && b <= 0x41u);
        if (t == 0) bfv = (__popcll(m2) >= 56) ? 1 : 0;
    }
    if (t < BK) hist[t] = 0;
    __syncthreads();
    int bf = bfv;
    int b = blockIdx.x, nb = b * BK;
    int m = qcnt[b]; if (m > QC) m = QC; if (m < 0) m = 0;
    const u32* q = qbuf + (size_t)b * QC;

    // stage self rows -> xs (f32), guarded for the partial last bucket
    if (bf) {
        const u32* xr = (const u32*)x + (size_t)nb * (IN_DIM / 2);
        int lim = ((N_NODES - nb < BK) ? (N_NODES - nb) : BK) * (IN_DIM / 2);
        for (int i = t; i < BK * (IN_DIM / 2); i += 512) {
            u32 w = (i < lim) ? xr[i] : 0u;
            int r = i >> 4, c = i & 15;
            xs[r][2 * c]     = bf2f((u16)w);
            xs[r][2 * c + 1] = bf2f((u16)(w >> 16));
        }
    } else {
        const float* xr = (const float*)x + (size_t)nb * IN_DIM;
        int lim = ((N_NODES - nb < BK) ? (N_NODES - nb) : BK) * IN_DIM;
        for (int i = t; i < BK * IN_DIM; i += 512)
            xs[i >> 5][i & 31] = (i < lim) ? xr[i] : 0.0f;
    }

    // ---- counting sort: histogram -> scan -> scatter ----
    for (int i = t; i < m; i += 512)
        atomicAdd(&hist[q[i] & 127], 1);          // ~2K atomics total, cheap
    __syncthreads();
    int inc = 0, v = 0;
    if (t < 128) {                                 // 2-wave scan of 128 bins
        v = hist[t]; inc = v;
        #pragma unroll
        for (int o = 1; o < 64; o <<= 1) {
            int y = __shfl_up(inc, o, 64);
            if ((t & 63) >= o) inc += y;
        }
        if (t == 63) wtot = inc;
    }
    __syncthreads();
    if (t < 128) {
        int ex = ((t >= 64) ? wtot : 0) + inc - v;
        pos[t] = ex; pcur[t] = ex;
    }
    __syncthreads();
    for (int i = t; i < m; i += 512) {            // scatter src into sorted lists
        u32 u = q[i];                             // L2-hot second pass
        int p = atomicAdd(&pcur[u & 127], 1);
        srt[p] = u >> 7;
    }
    __syncthreads();

    // ---- per-pair gather (R0-proven loop, LDS slot lists) + dense + proj ----
    int wid = t >> 6, lane = t & 63;               // wid 0..7
    int half = lane >> 5, g2 = (lane >> 3) & 3, l = lane & 7;
    int o = lane;
    float bb = tb1[o];
    for (int pr = 0; pr < 8; pr++) {
        int s0 = pr * 16 + wid * 2;
        int ns = s0 + half;
        int st = pos[ns], deg = hist[ns];
        float a0 = 0, a1 = 0, a2 = 0, a3 = 0;
        float c0 = 0, c1 = 0, c2 = 0, c3 = 0;
        float d0 = 0, d1 = 0, d2 = 0, d3 = 0;
        float e0 = 0, e1 = 0, e2 = 0, e3 = 0;
        int j = g2;
        for (; j + 12 < deg; j += 16) {   // 4 independent neighbor loads in flight
            int sA = (int)srt[st + j];
            int sB = (int)srt[st + j + 4];
            int sC = (int)srt[st + j + 8];
            int sD = (int)srt[st + j + 12];
            if (bf) {
                ushort4 vA = reinterpret_cast<const ushort4*>((const u16*)x + (size_t)sA * IN_DIM)[l];
                ushort4 vB = reinterpret_cast<const ushort4*>((const u16*)x + (size_t)sB * IN_DIM)[l];
                ushort4 vC = reinterpret_cast<const ushort4*>((const u16*)x + (size_t)sC * IN_DIM)[l];
                ushort4 vD = reinterpret_cast<const ushort4*>((const u16*)x + (size_t)sD * IN_DIM)[l];
                a0 += bf2f(vA.x); a1 += bf2f(vA.y); a2 += bf2f(vA.z); a3 += bf2f(vA.w);
                c0 += bf2f(vB.x); c1 += bf2f(vB.y); c2 += bf2f(vB.z); c3 += bf2f(vB.w);
                d0 += bf2f(vC.x); d1 += bf2f(vC.y); d2 += bf2f(vC.z); d3 += bf2f(vC.w);
                e0 += bf2f(vD.x); e1 += bf2f(vD.y); e2 += bf2f(vD.z); e3 += bf2f(vD.w);
            } else {
                float4 vA = reinterpret_cast<const float4*>((const float*)x + (size_t)sA * IN_DIM)[l];
                float4 vB = reinterpret_cast<const float4*>((const float*)x + (size_t)sB * IN_DIM)[l];
                float4 vC = reinterpret_cast<const float4*>((const float*)x + (size_t)sC * IN_DIM)[l];
                float4 vD = reinterpret_cast<const float4*>((const float*)x + (size_t)sD * IN_DIM)[l];
                a0 += vA.x; a1 += vA.y; a2 += vA.z; a3 += vA.w;
                c0 += vB.x; c1 += vB.y; c2 += vB.z; c3 += vB.w;
                d0 += vC.x; d1 += vC.y; d2 += vC.z; d3 += vC.w;
                e0 += vD.x; e1 += vD.y; e2 += vD.z; e3 += vD.w;
            }
        }
        for (; j + 4 < deg; j += 8) {     // 2-way remainder
            int sA = (int)srt[st + j];
            int sB = (int)srt[st + j + 4];
            if (bf) {
                ushort4 vA = reinterpret_cast<const ushort4*>((const u16*)x + (size_t)sA * IN_DIM)[l];
                ushort4 vB = reinterpret_cast<const ushort4*>((const u16*)x + (size_t)sB * IN_DIM)[l];
                a0 += bf2f(vA.x); a1 += bf2f(vA.y); a2 += bf2f(vA.z); a3 += bf2f(vA.w);
                c0 += bf2f(vB.x); c1 += bf2f(vB.y); c2 += bf2f(vB.z); c3 += bf2f(vB.w);
            } else {
                float4 vA = reinterpret_cast<const float4*>((const float*)x + (size_t)sA * IN_DIM)[l];
                float4 vB = reinterpret_cast<const float4*>((const float*)x + (size_t)sB * IN_DIM)[l];
                a0 += vA.x; a1 += vA.y; a2 += vA.z; a3 += vA.w;
                c0 += vB.x; c1 += vB.y; c2 += vB.z; c3 += vB.w;
            }
        }
        if (j < deg) {                    // tail (at most one per group)
            int s = (int)srt[st + j];
            if (bf) {
                ushort4 vv = reinterpret_cast<const ushort4*>((const u16*)x + (size_t)s * IN_DIM)[l];
                a0 += bf2f(vv.x); a1 += bf2f(vv.y); a2 += bf2f(vv.z); a3 += bf2f(vv.w);
            } else {
                float4 vv = reinterpret_cast<const float4*>((const float*)x + (size_t)s * IN_DIM)[l];
                a0 += vv.x; a1 += vv.y; a2 += vv.z; a3 += vv.w;
            }
        }
        a0 += c0 + d0 + e0;
        a1 += c1 + d1 + e1;
        a2 += c2 + d2 + e2;
        a3 += c3 + d3 + e3;
        a0 += __shfl_xor(a0, 8, 64);  a0 += __shfl_xor(a0, 16, 64);
        a1 += __shfl_xor(a1, 8, 64);  a1 += __shfl_xor(a1, 16, 64);
        a2 += __shfl_xor(a2, 8, 64);  a2 += __shfl_xor(a2, 16, 64);
        a3 += __shfl_xor(a3, 8, 64);  a3 += __shfl_xor(a3, 16, 64);
        if (g2 == 0) {                    // wave-private: no barrier needed
            aggw[wid][half][4 * l + 0] = a0; aggw[wid][half][4 * l + 1] = a1;
            aggw[wid][half][4 * l + 2] = a2; aggw[wid][half][4 * l + 3] = a3;
        }
        // dense layer 1 (each lane = output o, both nodes of the pair)
        float rd0 = 1.0f / fmaxf((float)hist[s0], 1.0f);
        float rd1 = 1.0f / fmaxf((float)hist[s0 + 1], 1.0f);
        float acc0 = bb, acc1 = bb;
        #pragma unroll 8
        for (int k = 0; k < IN_DIM; k++) {
            float wl = tW1l[k * HID_DIM + o];
            float wr = tW1r[k * HID_DIM + o];
            acc0 += (aggw[wid][0][k] * rd0) * wl + xs[s0][k] * wr;
            acc1 += (aggw[wid][1][k] * rd1) * wl + xs[s0 + 1][k] * wr;
        }
        hb[wid * 2][o]     = fmaxf(acc0, 0.0f);   // wave-private rows
        hb[wid * 2 + 1][o] = fmaxf(acc1, 0.0f);
        // layer-2 projections: g = h@W2l^T (bf16-packed), r = h@W2r^T + b2
        int hs = wid * 2 + half;
        float ga = 0.0f, ra = 0.0f;
        #pragma unroll 4
        for (int mm = 0; mm < 16; mm++) {
            int k = g2 * 16 + mm;
            float hv = hb[hs][k];
            ga += hv * tW2l[k * OUT_DIM + l];
            ra += hv * tW2r[k * OUT_DIM + l];
        }
        ga += __shfl_xor(ga, 8, 64);  ga += __shfl_xor(ga, 16, 64);
        ra += __shfl_xor(ra, 8, 64);  ra += __shfl_xor(ra, 16, 64);
        int n = nb + ns;
        if (g2 == 0 && n < N_NODES) {
            __builtin_nontemporal_store(f2bf(ga), &gbuf[(size_t)n * OUT_DIM + l]);
            __builtin_nontemporal_store(ra + tb2[l], &rbuf[(size_t)n * OUT_DIM + l]);
        }
    }
}

// ---- Layer 2 (R5-proven): one bucket per block. Counting sort, then gather
//      g[src] rows (L2-resident 1.6MB) with the 8-lane/node 4-way-ILP loop. ----
__global__ __launch_bounds__(256) void k_l2(
    const u16* __restrict__ gbuf, const float* __restrict__ rbuf,
    const int* __restrict__ qcnt, const u32* __restrict__ qbuf,
    const u32* __restrict__ xw, void* __restrict__ out)
{
    __shared__ int hist[BK], pos[BK], pcur[BK];
    __shared__ u32 srt[QC];
    __shared__ int wtot, bfv;
    int t = threadIdx.x;
    if (t < 64) {   // output-dtype probe (proven)
        u32 w = xw[t];
        u32 b = (w >> 8) & 0x7fu;
        ull m2 = __ballot(b >= 0x38u && b <= 0x41u);
        if (t == 0) bfv = (__popcll(m2) >= 56) ? 1 : 0;
    }
    if (t < BK) hist[t] = 0;
    __syncthreads();
    int b = blockIdx.x, nb = b * BK;
    int m = qcnt[b]; if (m > QC) m = QC; if (m < 0) m = 0;
    const u32* q = qbuf + (size_t)b * QC;

    for (int i = t; i < m; i += 256)
        atomicAdd(&hist[q[i] & 127], 1);
    __syncthreads();
    int inc = 0, v = 0;
    if (t < 128) {
        v = hist[t]; inc = v;
        #pragma unroll
        for (int o = 1; o < 64; o <<= 1) {
            int y = __shfl_up(inc, o, 64);
            if ((t & 63) >= o) inc += y;
        }
        if (t == 63) wtot = inc;
    }
    __syncthreads();
    if (t < 128) {
        int ex = ((t >= 64) ? wtot : 0) + inc - v;
        pos[t] = ex; pcur[t] = ex;
    }
    __syncthreads();
    for (int i = t; i < m; i += 256) {
        u32 u = q[i];
        int p = atomicAdd(&pcur[u & 127], 1);
        srt[p] = u >> 7;
    }
    __syncthreads();

    int grp = t >> 3, l = t & 7;          // 32 groups x 8 lanes
    for (int r = 0; r < 4; r++) {
        int ns = grp * 4 + r;             // node slot 0..127
        int st = pos[ns], deg = hist[ns];
        float a0 = 0.0f, a1 = 0.0f, a2 = 0.0f, a3 = 0.0f;
        int j = 0;
        for (; j + 3 < deg; j += 4) {
            int v0 = (int)srt[st + j];
            int v1 = (int)srt[st + j + 1];
            int v2 = (int)srt[st + j + 2];
            int v3 = (int)srt[st + j + 3];
            a0 += bf2f(gbuf[(size_t)v0 * OUT_DIM + l]);
            a1 += bf2f(gbuf[(size_t)v1 * OUT_DIM + l]);
            a2 += bf2f(gbuf[(size_t)v2 * OUT_DIM + l]);
            a3 += bf2f(gbuf[(size_t)v3 * OUT_DIM + l]);
        }
        for (; j < deg; j++) a0 += bf2f(gbuf[(size_t)srt[st + j] * OUT_DIM + l]);
        int n = nb + ns;
        if (n < N_NODES) {
            float res = (a0 + a1 + a2 + a3) / fmaxf((float)deg, 1.0f)
                      + rbuf[(size_t)n * OUT_DIM + l];
            size_t oi = (size_t)n * OUT_DIM + l;
            if (bfv) ((u16*)out)[oi] = f2bf(res);
            else     ((float*)out)[oi] = res;
        }
    }
}

extern "C" void kernel_launch(void* const* d_in, const int* in_sizes, int n_in,
                              void* d_out, int out_size, void* d_ws, size_t ws_size,
                              hipStream_t stream) {
    const void* x   = d_in[0];
    const int*  ei  = (const int*)d_in[1];
    const void* W1l = d_in[2];
    const void* b1  = d_in[3];
    const void* W1r = d_in[4];
    const void* W2l = d_in[5];
    const void* b2  = d_in[6];
    const void* W2r = d_in[7];

    // ws layout (4B units); total ~13 MB (ws >= 64.4 MB proven earlier)
    int* qcnt    = (int*)d_ws;                       // 1024 (memset, 782 used)
    float* tW1l  = (float*)(qcnt + 1024);            // 2048
    float* tW1r  = tW1l + IN_DIM * HID_DIM;          // 2048
    float* tW2l  = tW1r + IN_DIM * HID_DIM;          // 512
    float* tW2r  = tW2l + HID_DIM * OUT_DIM;         // 512
    float* tb1   = tW2r + HID_DIM * OUT_DIM;         // 64
    float* tb2   = tb1 + HID_DIM;                    // 8
    u32* qbuf    = (u32*)(tb2 + OUT_DIM);            // NBKT*QC (8.0 MB, 16B-aligned)
    u16* gbuf    = (u16*)(qbuf + (size_t)NBKT * QC);           // N*8 u16 (1.6 MB)
    float* rbuf  = (float*)(gbuf + (size_t)N_NODES * OUT_DIM); // N*8 f32 (3.2 MB)

    // zero qcnt only (4 KB)
    hipMemsetAsync(d_ws, 0, 1024 * sizeof(int), stream);

    k_part2<<<NCHUNK, 256, 0, stream>>>(ei, (const u32*)x,
                                        W1l, b1, W1r, W2l, b2, W2r,
                                        qcnt, qbuf,
                                        tW1l, tW1r, tW2l, tW2r, tb1, tb2);
    k_l1<<<NBKT, 512, 0, stream>>>(x, qcnt, qbuf,
                                   tW1l, tW1r, tW2l, tW2r, tb1, tb2,
                                   gbuf, rbuf, (const u32*)x);
    k_l2<<<NBKT, 256, 0, stream>>>(gbuf, rbuf, qcnt, qbuf,
                                   (const u32*)x, d_out);
}

// Round 8
// 213.898 us; speedup vs baseline: 1.2727x; 1.0150x over previous
//
#include <hip/hip_runtime.h>

#define N_NODES 100000
#define N_EDGES 1600000
#define IN_DIM 32
#define HID_DIM 64
#define OUT_DIM 8
#define BK 64                         // dst nodes per bucket (R8: halved for 2x blocks)
#define NBKT ((N_NODES + BK - 1) / BK)    // 1563
#define QC 1280                       // per-bucket queue cap (mean 1024, +8 sigma)
#define CHUNK 4096                    // edges per k_part2 block
#define NCHUNK ((N_EDGES + CHUNK - 1) / CHUNK)   // 391

typedef unsigned short u16;
typedef unsigned int u32;
typedef unsigned long long ull;

__device__ __forceinline__ float bf2f(u16 v) {
    return __uint_as_float(((u32)v) << 16);
}

__device__ __forceinline__ u16 f2bf(float f) {
    u32 u = __float_as_uint(f);
    u32 lsb = (u >> 16) & 1u;
    u += 0x7fffu + lsb;
    return (u16)(u >> 16);
}

__device__ __forceinline__ float ldf(const void* p, size_t i, int bf) {
    return bf ? bf2f(((const u16*)p)[i]) : ((const float*)p)[i];
}

// ---- Phase A (R3/R5-proven): dtype probe + weight transpose + single-pass
//      partition of edges into 1563 dst-buckets of 64 nodes ((src<<6)|d6). ----
__global__ __launch_bounds__(256) void k_part2(
    const int* __restrict__ ei, const u32* __restrict__ xw,
    const void* __restrict__ W1l, const void* __restrict__ b1,
    const void* __restrict__ W1r,
    const void* __restrict__ W2l, const void* __restrict__ b2,
    const void* __restrict__ W2r,
    int* __restrict__ qcnt, u32* __restrict__ qbuf,
    float* __restrict__ tW1l, float* __restrict__ tW1r,
    float* __restrict__ tW2l, float* __restrict__ tW2r,
    float* __restrict__ tb1, float* __restrict__ tb2)
{
    __shared__ int shv, bfv;
    __shared__ int hist[NBKT], gbase[NBKT], lcur[NBKT];   // 18.8 KB
    int t = threadIdx.x;
    if (t < 64) {   // proven dtype probe, executed per block (same data)
        int v = ei[2 * t + 1];
        ull m1 = __ballot(v == 0);
        u32 wd = xw[t];
        u32 b = (wd >> 8) & 0x7fu;
        ull m2 = __ballot(b >= 0x38u && b <= 0x41u);
        if (t == 0) {
            shv = (m1 == ~0ULL) ? 1 : 0;
            bfv = (__popcll(m2) >= 56) ? 1 : 0;
        }
    }
    for (int i = t; i < NBKT; i += 256) { hist[i] = 0; lcur[i] = 0; }
    __syncthreads();
    int sh = shv, bf = bfv;

    if (blockIdx.x < 16) {        // weight transpose duty (R11-proven indexing)
        for (int i = blockIdx.x * 256 + t; i < HID_DIM * IN_DIM; i += 16 * 256) {
            int o = i / IN_DIM, k = i % IN_DIM;
            tW1l[k * HID_DIM + o] = ldf(W1l, i, bf);
            tW1r[k * HID_DIM + o] = ldf(W1r, i, bf);
        }
        for (int i = blockIdx.x * 256 + t; i < OUT_DIM * HID_DIM; i += 16 * 256) {
            int o = i / HID_DIM, k = i % HID_DIM;
            tW2l[k * OUT_DIM + o] = ldf(W2l, i, bf);
            tW2r[k * OUT_DIM + o] = ldf(W2r, i, bf);
        }
        if (blockIdx.x == 0) {
            if (t < HID_DIM) tb1[t] = ldf(b1, t, bf);
            if (t < OUT_DIM) tb2[t] = ldf(b2, t, bf);
        }
    }

    // edge partition (register-staged, R10-proven shape)
    int e0 = blockIdx.x * CHUNK;
    int myd[16], mys[16];
    #pragma unroll
    for (int i = 0; i < 16; i++) {
        int e = e0 + i * 256 + t;
        if (e < N_EDGES) {
            size_t off = (size_t)e << sh;
            mys[i] = ei[off];
            int d = ei[((size_t)N_EDGES << sh) + off];
            myd[i] = d;
            atomicAdd(&hist[d >> 6], 1);
        } else myd[i] = -1;
    }
    __syncthreads();
    for (int i = t; i < NBKT; i += 256) {
        int h = hist[i];
        gbase[i] = h ? atomicAdd(&qcnt[i], h) : 0;
    }
    __syncthreads();
    #pragma unroll
    for (int i = 0; i < 16; i++) {
        int d = myd[i];
        if (d >= 0) {
            int bk = d >> 6;
            int p = gbase[bk] + atomicAdd(&lcur[bk], 1);
            if (p < QC)
                qbuf[(size_t)bk * QC + p] = ((u32)mys[i] << 6) | (u32)(d & 63);
        }
    }
}

// ---- Layer 1: one 64-node bucket per block, 256 threads (R5-proven inner
//      structure). R7 lesson: fat 512-thread blocks don't raise residency
//      (occ stuck ~30%, dur flat); smaller buckets double the block count
//      instead: 1563 blocks -> ~6 blocks/CU x 4 waves ~ 24 waves/CU.
//      LDS ~18KB (was 33KB) so LDS caps at 8 blocks/CU, grid is the limit.
//      (1) LDS counting sort by dst (64 bins, 1-wave scan).
//      (2) R0-proven register-accumulate gather (4-way ILP) from sorted LDS.
//      (3) R3-proven dense1+relu+proj2 per node pair, wave-private bufs. ----
__global__ __launch_bounds__(256, 4) void k_l1(
    const void* __restrict__ x,
    const int* __restrict__ qcnt, const u32* __restrict__ qbuf,
    const float* __restrict__ tW1l, const float* __restrict__ tW1r,
    const float* __restrict__ tW2l, const float* __restrict__ tW2r,
    const float* __restrict__ tb1, const float* __restrict__ tb2,
    u16* __restrict__ gbuf, float* __restrict__ rbuf,
    const u32* __restrict__ xw)
{
    __shared__ int hist[BK], pos[BK], pcur[BK];   // 0.75 KB
    __shared__ u32 srt[QC];                 // 5.1 KB sorted src lists
    __shared__ float xs[BK][IN_DIM];        // 8 KB self rows (f32)
    __shared__ float aggw[4][2][IN_DIM];    // 1 KB wave-private agg pair
    __shared__ float hb[8][HID_DIM + 1];    // 2 KB wave-private h rows
    __shared__ int bfv;

    int t = threadIdx.x;
    if (t < 64) {   // dtype probe (proven)
        u32 wd = xw[t];
        u32 b = (wd >> 8) & 0x7fu;
        ull m2 = __ballot(b >= 0x38u && b <= 0x41u);
        if (t == 0) bfv = (__popcll(m2) >= 56) ? 1 : 0;
    }
    if (t < BK) hist[t] = 0;
    __syncthreads();
    int bf = bfv;
    int b = blockIdx.x, nb = b * BK;
    int m = qcnt[b]; if (m > QC) m = QC; if (m < 0) m = 0;
    const u32* q = qbuf + (size_t)b * QC;

    // stage self rows -> xs (f32), guarded for the partial last bucket
    if (bf) {
        const u32* xr = (const u32*)x + (size_t)nb * (IN_DIM / 2);
        int lim = ((N_NODES - nb < BK) ? (N_NODES - nb) : BK) * (IN_DIM / 2);
        for (int i = t; i < BK * (IN_DIM / 2); i += 256) {
            u32 w = (i < lim) ? xr[i] : 0u;
            int r = i >> 4, c = i & 15;
            xs[r][2 * c]     = bf2f((u16)w);
            xs[r][2 * c + 1] = bf2f((u16)(w >> 16));
        }
    } else {
        const float* xr = (const float*)x + (size_t)nb * IN_DIM;
        int lim = ((N_NODES - nb < BK) ? (N_NODES - nb) : BK) * IN_DIM;
        for (int i = t; i < BK * IN_DIM; i += 256)
            xs[i >> 5][i & 31] = (i < lim) ? xr[i] : 0.0f;
    }

    // ---- counting sort: histogram -> 1-wave scan (64 bins) -> scatter ----
    for (int i = t; i < m; i += 256)
        atomicAdd(&hist[q[i] & 63], 1);           // ~1K atomics total, cheap
    __syncthreads();
    if (t < 64) {
        int v = hist[t];
        int inc = v;
        #pragma unroll
        for (int o = 1; o < 64; o <<= 1) {
            int y = __shfl_up(inc, o, 64);
            if (t >= o) inc += y;
        }
        int ex = inc - v;
        pos[t] = ex; pcur[t] = ex;
    }
    __syncthreads();
    for (int i = t; i < m; i += 256) {            // scatter src into sorted lists
        u32 u = q[i];                             // L2-hot second pass
        int p = atomicAdd(&pcur[u & 63], 1);
        srt[p] = u >> 6;
    }
    __syncthreads();

    // ---- per-pair gather (R0-proven loop, LDS slot lists) + dense + proj ----
    int wid = t >> 6, lane = t & 63;               // wid 0..3
    int half = lane >> 5, g2 = (lane >> 3) & 3, l = lane & 7;
    int o = lane;
    float bb = tb1[o];
    for (int pr = 0; pr < 8; pr++) {
        int s0 = pr * 8 + wid * 2;
        int ns = s0 + half;
        int st = pos[ns], deg = hist[ns];
        float a0 = 0, a1 = 0, a2 = 0, a3 = 0;
        float c0 = 0, c1 = 0, c2 = 0, c3 = 0;
        float d0 = 0, d1 = 0, d2 = 0, d3 = 0;
        float e0 = 0, e1 = 0, e2 = 0, e3 = 0;
        int j = g2;
        for (; j + 12 < deg; j += 16) {   // 4 independent neighbor loads in flight
            int sA = (int)srt[st + j];
            int sB = (int)srt[st + j + 4];
            int sC = (int)srt[st + j + 8];
            int sD = (int)srt[st + j + 12];
            if (bf) {
                ushort4 vA = reinterpret_cast<const ushort4*>((const u16*)x + (size_t)sA * IN_DIM)[l];
                ushort4 vB = reinterpret_cast<const ushort4*>((const u16*)x + (size_t)sB * IN_DIM)[l];
                ushort4 vC = reinterpret_cast<const ushort4*>((const u16*)x + (size_t)sC * IN_DIM)[l];
                ushort4 vD = reinterpret_cast<const ushort4*>((const u16*)x + (size_t)sD * IN_DIM)[l];
                a0 += bf2f(vA.x); a1 += bf2f(vA.y); a2 += bf2f(vA.z); a3 += bf2f(vA.w);
                c0 += bf2f(vB.x); c1 += bf2f(vB.y); c2 += bf2f(vB.z); c3 += bf2f(vB.w);
                d0 += bf2f(vC.x); d1 += bf2f(vC.y); d2 += bf2f(vC.z); d3 += bf2f(vC.w);
                e0 += bf2f(vD.x); e1 += bf2f(vD.y); e2 += bf2f(vD.z); e3 += bf2f(vD.w);
            } else {
                float4 vA = reinterpret_cast<const float4*>((const float*)x + (size_t)sA * IN_DIM)[l];
                float4 vB = reinterpret_cast<const float4*>((const float*)x + (size_t)sB * IN_DIM)[l];
                float4 vC = reinterpret_cast<const float4*>((const float*)x + (size_t)sC * IN_DIM)[l];
                float4 vD = reinterpret_cast<const float4*>((const float*)x + (size_t)sD * IN_DIM)[l];
                a0 += vA.x; a1 += vA.y; a2 += vA.z; a3 += vA.w;
                c0 += vB.x; c1 += vB.y; c2 += vB.z; c3 += vB.w;
                d0 += vC.x; d1 += vC.y; d2 += vC.z; d3 += vC.w;
                e0 += vD.x; e1 += vD.y; e2 += vD.z; e3 += vD.w;
            }
        }
        for (; j + 4 < deg; j += 8) {     // 2-way remainder
            int sA = (int)srt[st + j];
            int sB = (int)srt[st + j + 4];
            if (bf) {
                ushort4 vA = reinterpret_cast<const ushort4*>((const u16*)x + (size_t)sA * IN_DIM)[l];
                ushort4 vB = reinterpret_cast<const ushort4*>((const u16*)x + (size_t)sB * IN_DIM)[l];
                a0 += bf2f(vA.x); a1 += bf2f(vA.y); a2 += bf2f(vA.z); a3 += bf2f(vA.w);
                c0 += bf2f(vB.x); c1 += bf2f(vB.y); c2 += bf2f(vB.z); c3 += bf2f(vB.w);
            } else {
                float4 vA = reinterpret_cast<const float4*>((const float*)x + (size_t)sA * IN_DIM)[l];
                float4 vB = reinterpret_cast<const float4*>((const float*)x + (size_t)sB * IN_DIM)[l];
                a0 += vA.x; a1 += vA.y; a2 += vA.z; a3 += vA.w;
                c0 += vB.x; c1 += vB.y; c2 += vB.z; c3 += vB.w;
            }
        }
        if (j < deg) {                    // tail (at most one per group)
            int s = (int)srt[st + j];
            if (bf) {
                ushort4 vv = reinterpret_cast<const ushort4*>((const u16*)x + (size_t)s * IN_DIM)[l];
                a0 += bf2f(vv.x); a1 += bf2f(vv.y); a2 += bf2f(vv.z); a3 += bf2f(vv.w);
            } else {
                float4 vv = reinterpret_cast<const float4*>((const float*)x + (size_t)s * IN_DIM)[l];
                a0 += vv.x; a1 += vv.y; a2 += vv.z; a3 += vv.w;
            }
        }
        a0 += c0 + d0 + e0;
        a1 += c1 + d1 + e1;
        a2 += c2 + d2 + e2;
        a3 += c3 + d3 + e3;
        a0 += __shfl_xor(a0, 8, 64);  a0 += __shfl_xor(a0, 16, 64);
        a1 += __shfl_xor(a1, 8, 64);  a1 += __shfl_xor(a1, 16, 64);
        a2 += __shfl_xor(a2, 8, 64);  a2 += __shfl_xor(a2, 16, 64);
        a3 += __shfl_xor(a3, 8, 64);  a3 += __shfl_xor(a3, 16, 64);
        if (g2 == 0) {                    // wave-private: no barrier needed
            aggw[wid][half][4 * l + 0] = a0; aggw[wid][half][4 * l + 1] = a1;
            aggw[wid][half][4 * l + 2] = a2; aggw[wid][half][4 * l + 3] = a3;
        }
        // dense layer 1 (each lane = output o, both nodes of the pair)
        float rd0 = 1.0f / fmaxf((float)hist[s0], 1.0f);
        float rd1 = 1.0f / fmaxf((float)hist[s0 + 1], 1.0f);
        float acc0 = bb, acc1 = bb;
        #pragma unroll 8
        for (int k = 0; k < IN_DIM; k++) {
            float wl = tW1l[k * HID_DIM + o];
            float wr = tW1r[k * HID_DIM + o];
            acc0 += (aggw[wid][0][k] * rd0) * wl + xs[s0][k] * wr;
            acc1 += (aggw[wid][1][k] * rd1) * wl + xs[s0 + 1][k] * wr;
        }
        hb[wid * 2][o]     = fmaxf(acc0, 0.0f);   // wave-private rows
        hb[wid * 2 + 1][o] = fmaxf(acc1, 0.0f);
        // layer-2 projections: g = h@W2l^T (bf16-packed), r = h@W2r^T + b2
        int hs = wid * 2 + half;
        float ga = 0.0f, ra = 0.0f;
        #pragma unroll 4
        for (int mm = 0; mm < 16; mm++) {
            int k = g2 * 16 + mm;
            float hv = hb[hs][k];
            ga += hv * tW2l[k * OUT_DIM + l];
            ra += hv * tW2r[k * OUT_DIM + l];
        }
        ga += __shfl_xor(ga, 8, 64);  ga += __shfl_xor(ga, 16, 64);
        ra += __shfl_xor(ra, 8, 64);  ra += __shfl_xor(ra, 16, 64);
        int n = nb + ns;
        if (g2 == 0 && n < N_NODES) {
            __builtin_nontemporal_store(f2bf(ga), &gbuf[(size_t)n * OUT_DIM + l]);
            __builtin_nontemporal_store(ra + tb2[l], &rbuf[(size_t)n * OUT_DIM + l]);
        }
    }
}

// ---- Layer 2 (R5-proven structure, BK=64): counting sort, then gather
//      g[src] rows (L2-resident 1.6MB) with the 8-lane/node 4-way-ILP loop. ----
__global__ __launch_bounds__(256) void k_l2(
    const u16* __restrict__ gbuf, const float* __restrict__ rbuf,
    const int* __restrict__ qcnt, const u32* __restrict__ qbuf,
    const u32* __restrict__ xw, void* __restrict__ out)
{
    __shared__ int hist[BK], pos[BK], pcur[BK];
    __shared__ u32 srt[QC];
    __shared__ int bfv;
    int t = threadIdx.x;
    if (t < 64) {   // output-dtype probe (proven)
        u32 w = xw[t];
        u32 b = (w >> 8) & 0x7fu;
        ull m2 = __ballot(b >= 0x38u && b <= 0x41u);
        if (t == 0) bfv = (__popcll(m2) >= 56) ? 1 : 0;
    }
    if (t < BK) hist[t] = 0;
    __syncthreads();
    int b = blockIdx.x, nb = b * BK;
    int m = qcnt[b]; if (m > QC) m = QC; if (m < 0) m = 0;
    const u32* q = qbuf + (size_t)b * QC;

    for (int i = t; i < m; i += 256)
        atomicAdd(&hist[q[i] & 63], 1);
    __syncthreads();
    if (t < 64) {
        int v = hist[t];
        int inc = v;
        #pragma unroll
        for (int o = 1; o < 64; o <<= 1) {
            int y = __shfl_up(inc, o, 64);
            if (t >= o) inc += y;
        }
        int ex = inc - v;
        pos[t] = ex; pcur[t] = ex;
    }
    __syncthreads();
    for (int i = t; i < m; i += 256) {
        u32 u = q[i];
        int p = atomicAdd(&pcur[u & 63], 1);
        srt[p] = u >> 6;
    }
    __syncthreads();

    int grp = t >> 3, l = t & 7;          // 32 groups x 8 lanes
    for (int r = 0; r < 2; r++) {
        int ns = grp * 2 + r;             // node slot 0..63
        int st = pos[ns], deg = hist[ns];
        float a0 = 0.0f, a1 = 0.0f, a2 = 0.0f, a3 = 0.0f;
        int j = 0;
        for (; j + 3 < deg; j += 4) {
            int v0 = (int)srt[st + j];
            int v1 = (int)srt[st + j + 1];
            int v2 = (int)srt[st + j + 2];
            int v3 = (int)srt[st + j + 3];
            a0 += bf2f(gbuf[(size_t)v0 * OUT_DIM + l]);
            a1 += bf2f(gbuf[(size_t)v1 * OUT_DIM + l]);
            a2 += bf2f(gbuf[(size_t)v2 * OUT_DIM + l]);
            a3 += bf2f(gbuf[(size_t)v3 * OUT_DIM + l]);
        }
        for (; j < deg; j++) a0 += bf2f(gbuf[(size_t)srt[st + j] * OUT_DIM + l]);
        int n = nb + ns;
        if (n < N_NODES) {
            float res = (a0 + a1 + a2 + a3) / fmaxf((float)deg, 1.0f)
                      + rbuf[(size_t)n * OUT_DIM + l];
            size_t oi = (size_t)n * OUT_DIM + l;
            if (bfv) ((u16*)out)[oi] = f2bf(res);
            else     ((float*)out)[oi] = res;
        }
    }
}

extern "C" void kernel_launch(void* const* d_in, const int* in_sizes, int n_in,
                              void* d_out, int out_size, void* d_ws, size_t ws_size,
                              hipStream_t stream) {
    const void* x   = d_in[0];
    const int*  ei  = (const int*)d_in[1];
    const void* W1l = d_in[2];
    const void* b1  = d_in[3];
    const void* W1r = d_in[4];
    const void* W2l = d_in[5];
    const void* b2  = d_in[6];
    const void* W2r = d_in[7];

    // ws layout (4B units); total ~13 MB (ws >= 64.4 MB proven earlier)
    int* qcnt    = (int*)d_ws;                       // 2048 (memset, 1563 used)
    float* tW1l  = (float*)(qcnt + 2048);            // 2048
    float* tW1r  = tW1l + IN_DIM * HID_DIM;          // 2048
    float* tW2l  = tW1r + IN_DIM * HID_DIM;          // 512
    float* tW2r  = tW2l + HID_DIM * OUT_DIM;         // 512
    float* tb1   = tW2r + HID_DIM * OUT_DIM;         // 64
    float* tb2   = tb1 + HID_DIM;                    // 8
    u32* qbuf    = (u32*)(tb2 + OUT_DIM);            // NBKT*QC (8.0 MB, 16B-aligned)
    u16* gbuf    = (u16*)(qbuf + (size_t)NBKT * QC);           // N*8 u16 (1.6 MB)
    float* rbuf  = (float*)(gbuf + (size_t)N_NODES * OUT_DIM); // N*8 f32 (3.2 MB)

    // zero qcnt only (8 KB)
    hipMemsetAsync(d_ws, 0, 2048 * sizeof(int), stream);

    k_part2<<<NCHUNK, 256, 0, stream>>>(ei, (const u32*)x,
                                        W1l, b1, W1r, W2l, b2, W2r,
                                        qcnt, qbuf,
                                        tW1l, tW1r, tW2l, tW2r, tb1, tb2);
    k_l1<<<NBKT, 256, 0, stream>>>(x, qcnt, qbuf,
                                   tW1l, tW1r, tW2l, tW2r, tb1, tb2,
                                   gbuf, rbuf, (const u32*)x);
    k_l2<<<NBKT, 256, 0, stream>>>(gbuf, rbuf, qcnt, qbuf,
                                   (const u32*)x, d_out);
}